// Round 16
// baseline (95.917 us; speedup 1.0000x reference)
//
#include <hip/hip_runtime.h>
#include <math.h>

#define NTOT 4096
#define BSZH 2048
#define DIMK 256
#define GY   32            // 4096/128 tiles per dimension

typedef __bf16 bf16x8 __attribute__((ext_vector_type(8)));
typedef float  f32x4  __attribute__((ext_vector_type(4)));

// fp32 -> bf16 fragment-major layout + row squared norms + zero out.
// Fragment layout: panel p = row>>4 (256 panels of 16 rows); within a panel,
// chunk g = k>>3 (32 chunks); chunk = 16 lanes x 16B: lane r gets
// f[p*16+r][g*8..g*8+7] as bf16x8. k_main loads a fragment as base+lane*16.
__global__ __launch_bounds__(256) void k_prep(const float* __restrict__ f,
                                              __bf16* __restrict__ fbf,
                                              float* __restrict__ sq,
                                              float* __restrict__ out) {
    if (blockIdx.x == 0 && threadIdx.x == 0) out[0] = 0.0f;
    const int tid   = threadIdx.x;
    const int panel = blockIdx.x;
    const int r  = tid >> 4;     // 0..15 row within panel
    const int gg = tid & 15;     // 0..15 k-group
    __shared__ __align__(16) __bf16 lp[4096];   // 8 KiB staging

    float s = 0.f;
    #pragma unroll
    for (int h = 0; h < 2; ++h) {
        int g = gg + h * 16;
        const float* src = f + (size_t)(panel * 16 + r) * DIMK + g * 8;
        float4 v0 = *(const float4*)(src);
        float4 v1 = *(const float4*)(src + 4);
        s += v0.x*v0.x + v0.y*v0.y + v0.z*v0.z + v0.w*v0.w
           + v1.x*v1.x + v1.y*v1.y + v1.z*v1.z + v1.w*v1.w;
        bf16x8 pk;
        pk[0] = (__bf16)v0.x; pk[1] = (__bf16)v0.y; pk[2] = (__bf16)v0.z; pk[3] = (__bf16)v0.w;
        pk[4] = (__bf16)v1.x; pk[5] = (__bf16)v1.y; pk[6] = (__bf16)v1.z; pk[7] = (__bf16)v1.w;
        *(bf16x8*)(lp + g * 128 + r * 8) = pk;
    }
    #pragma unroll
    for (int m = 1; m < 16; m <<= 1) s += __shfl_xor(s, m, 64);
    if (gg == 0) sq[panel * 16 + r] = s;
    __syncthreads();
    const bf16x8* srcv = (const bf16x8*)lp;
    bf16x8* dst = (bf16x8*)(fbf + (size_t)panel * 4096);
    dst[tid]       = srcv[tid];
    dst[tid + 256] = srcv[tid + 256];
}

// 128x128 tile per block, 8 waves (512 thr): wave (wr=wid>>2, wc=wid&3)
// computes a 64x32 sub-tile -> acc[4][2] = 32 VGPR. Natural live set fits
// the 128-VGPR / 4-waves-per-SIMD budget WITHOUT spill (round-10 fix:
// VGPR_Count=64 exposed acc spilling under the old 4x4 layout).
__global__ __launch_bounds__(512, 4) void k_main(const __bf16* __restrict__ fbf,
                                                 const int* __restrict__ labels,
                                                 const float* __restrict__ sq,
                                                 float4* __restrict__ part) {
    const int tid = threadIdx.x;
    const int wid = tid >> 6, lane = tid & 63;
    const int l15 = lane & 15, lg = lane >> 4;
    const int wr  = wid >> 2,  wc = wid & 3;
    const int bx = blockIdx.x, by = blockIdx.y;
    const int trow = bx * 128, tcol = by * 128;
    const bool tilediag = (bx == by);

    const char* base = (const char*)fbf + lane * 16;
    const char* arow = base + (size_t)(bx * 8 + wr * 4) * 8192;
    const char* brow = base + (size_t)(by * 8 + wc * 2) * 8192;

    f32x4 acc[4][2];
    #pragma unroll
    for (int i = 0; i < 4; ++i)
        #pragma unroll
        for (int j = 0; j < 2; ++j) acc[i][j] = (f32x4){0.f, 0.f, 0.f, 0.f};

    #pragma unroll
    for (int s = 0; s < 8; ++s) {
        bf16x8 av[4], bv[2];
        #pragma unroll
        for (int i = 0; i < 4; ++i)
            av[i] = *(const bf16x8*)(arow + (size_t)i * 8192 + s * 1024);
        #pragma unroll
        for (int j = 0; j < 2; ++j)
            bv[j] = *(const bf16x8*)(brow + (size_t)j * 8192 + s * 1024);
        #pragma unroll
        for (int i = 0; i < 4; ++i)
            #pragma unroll
            for (int j = 0; j < 2; ++j)
                acc[i][j] = __builtin_amdgcn_mfma_f32_16x16x32_bf16(av[i], bv[j], acc[i][j], 0, 0, 0);
    }

    // ---- epilogue (row partials only) ----
    float cb2[2], cb2p[2], cb01[2], cinv[2]; int clab[2], cloc[2];
    #pragma unroll
    for (int j = 0; j < 2; ++j) {
        int lc  = wc * 32 + j * 16 + l15;
        int col = tcol + lc;
        float b2 = sq[col];
        cloc[j] = lc;
        cb2[j]  = b2;
        cb2p[j] = fmaf(0.01f, b2, 1.0f);
        cb01[j] = 0.01f * b2;
        cinv[j] = __builtin_amdgcn_rsqf(fmaxf(b2, 1e-24f));
        clab[j] = labels[col & (BSZH - 1)];
    }

    __shared__ float redR[2][4][64][3];   // [wr][wc][row_local][T,P,N]

    #pragma unroll
    for (int i = 0; i < 4; ++i) {
        float rT[4], rP[4], rN[4];
        float ra2[4], rinv[4], Bv[4], B2v[4]; int rlab[4];
        #pragma unroll
        for (int t = 0; t < 4; ++t) {
            rT[t] = 0.f; rP[t] = 0.f; rN[t] = 0.f;
            int row = trow + wr * 64 + i * 16 + lg * 4 + t;
            float a2 = sq[row];
            ra2[t]  = a2;
            rinv[t] = __builtin_amdgcn_rsqf(fmaxf(a2, 1e-24f));
            rlab[t] = labels[row & (BSZH - 1)];
            float B = fmaf(-0.01f, a2, 1.0f);
            Bv[t] = B; B2v[t] = B * B;
        }
        #pragma unroll
        for (int j = 0; j < 2; ++j) {
            f32x4 a = acc[i][j];
            #pragma unroll
            for (int t = 0; t < 4; ++t) {
                float g   = a[t];
                float A   = fmaf(-0.02f, g, cb2p[j]);          // 1 + 2c*ab + c*b2
                float den = fmaf(-cb01[j], Bv[t], A);          // 1 + 2c*ab + c^2*a2*b2
                float AB  = A * Bv[t];
                float num = fmaf(ra2[t] * A, A, fmaf(-(g + g), AB, cb2[j] * B2v[t]));
                float sdt = __builtin_amdgcn_sqrtf(fmaxf(num, 1e-12f));
                float h   = 0.1f * sdt;                        // x*den, x <= ~0.25
                float r   = (den + h) * __builtin_amdgcn_rcpf(den - h);
                float ang = g * rinv[t] * cinv[j];
                // sim = -49.5105*log2(r) + 7.142857*ang ; e^sim = exp2(tq)
                float tq  = fmaf(-71.4285714f, __builtin_amdgcn_logf(r), 10.3058781f * ang);
                float e   = __builtin_amdgcn_exp2f(tq);
                bool  dg  = tilediag && (wr * 64 + i * 16 + lg * 4 + t == cloc[j]);
                bool  pos = (!dg) && (rlab[t] == clab[j]);
                rT[t] += dg ? 0.f : e;
                rP[t] += pos ? 0.69314718f * tq : 0.f;         // sim
                rN[t] += pos ? 1.f : 0.f;
            }
        }
        #pragma unroll
        for (int t = 0; t < 4; ++t) {
            float T = rT[t], Pp = rP[t], Nn = rN[t];
            #pragma unroll
            for (int m = 1; m < 16; m <<= 1) {
                T  += __shfl_xor(T,  m, 64);
                Pp += __shfl_xor(Pp, m, 64);
                Nn += __shfl_xor(Nn, m, 64);
            }
            if (l15 == 0) {
                int rl = i * 16 + lg * 4 + t;
                redR[wr][wc][rl][0] = T; redR[wr][wc][rl][1] = Pp; redR[wr][wc][rl][2] = Nn;
            }
        }
    }
    __syncthreads();
    if (tid < 128) {
        int w = tid >> 6, rl = tid & 63;
        float T = 0.f, Pp = 0.f, Nn = 0.f;
        #pragma unroll
        for (int c = 0; c < 4; ++c) {
            T  += redR[w][c][rl][0];
            Pp += redR[w][c][rl][1];
            Nn += redR[w][c][rl][2];
        }
        part[(size_t)by * NTOT + trow + w * 64 + rl] = make_float4(T, Pp, Nn, 0.f);
    }
}

// combine 32 tile partials per row. Row max M == diag == 7.142857 exactly
// (dsim<=0, ang<=1, equality only on the diagonal), so the stop_gradient
// shift cancels and log(sum exp_logits + 1e-10) folds to
// log(T + 1e-10*e^M) with 1e-10*e^M = 1.265037e-7.
__global__ void k_final(const float4* __restrict__ part, float* __restrict__ out) {
    int row = blockIdx.x * 256 + threadIdx.x;
    float T = 0.f, P = 0.f, N = 0.f;
    #pragma unroll
    for (int k = 0; k < GY; ++k) {
        float4 p = part[(size_t)k * NTOT + row];
        T += p.x; P += p.y; N += p.z;
    }
    float v = (N < 1e-6f) ? 0.f
            : (__logf(T + 1.265037e-7f) - P / N) * (1.0f / NTOT);
    #pragma unroll
    for (int off = 32; off > 0; off >>= 1) v += __shfl_xor(v, off, 64);
    __shared__ float wsum[4];
    int wd = threadIdx.x >> 6, lane = threadIdx.x & 63;
    if (lane == 0) wsum[wd] = v;
    __syncthreads();
    if (threadIdx.x == 0) atomicAdd(out, wsum[0] + wsum[1] + wsum[2] + wsum[3]);
}

extern "C" void kernel_launch(void* const* d_in, const int* in_sizes, int n_in,
                              void* d_out, int out_size, void* d_ws, size_t ws_size,
                              hipStream_t stream) {
    const float* f      = (const float*)d_in[0];
    const int*   labels = (const int*)d_in[1];
    float* out = (float*)d_out;

    __bf16* fbf  = (__bf16*)d_ws;                                            // 2 MiB
    float*  sq   = (float*)((char*)d_ws + (size_t)NTOT * DIMK * 2);          // 16 KiB
    float4* part = (float4*)((char*)d_ws + (size_t)NTOT * DIMK * 2 + 65536); // 2 MiB

    k_prep <<<dim3(NTOT / 16), dim3(256), 0, stream>>>(f, fbf, sq, out);
    k_main <<<dim3(GY, GY),    dim3(512), 0, stream>>>(fbf, labels, sq, part);
    k_final<<<dim3(NTOT / 256), dim3(256), 0, stream>>>(part, out);
}